// Round 1
// baseline (2432.321 us; speedup 1.0000x reference)
//
#include <hip/hip_runtime.h>
#include <hip/hip_bf16.h>
#include <cstdint>
#include <cstddef>

// VQ-EMA fused pipeline for B=32768, K=8192, D=1024 on gfx950.
// Heavy part: sim = (z/||z||) @ (cb/||cb||)^T argmax over K, done as a
// split-fp16 MFMA GEMM (hi*hi + hi*lo + lo*hi) fused with per-row argmax.
// Scale-invariance of argmax lets us fold a x64 scaling into the fp16 split
// (keeps lo in fp16-normal range) and never normalize the sims back.

#define B_N 32768
#define K_N 8192
#define D_N 1024
#define DECAYF 0.99f
#define OMDECAYF 0.01f   // float(1.0 - 0.99) == 0.01f bitwise
#define EPSF 1e-5f
#define NORM_EPSF 1e-12f

#define BT 128           // b rows per block tile
#define KT 128           // k cols per block tile
#define DT 32            // d per K-step (one 16x16x32 MFMA K)
#define LDT 40           // LDS stride in halves (32 + 8 pad -> 16B aligned rows, 2-way banks)
#define NKT (K_N / KT)   // 64 k-tiles

typedef _Float16 f16x8 __attribute__((ext_vector_type(8)));
typedef _Float16 f16x4 __attribute__((ext_vector_type(4)));
typedef float f32x4 __attribute__((ext_vector_type(4)));

// ---------------------------------------------------------------- row scales
// scale[row] = 64 / max(||x_row||, 1e-12); one block per row, 256 thr, D=1024.
__global__ __launch_bounds__(256) void row_scale_kernel(
    const float* __restrict__ x, float* __restrict__ scale) {
  const int row = blockIdx.x;
  const float4 v =
      reinterpret_cast<const float4*>(x + (size_t)row * D_N)[threadIdx.x];
  float ss = v.x * v.x + v.y * v.y + v.z * v.z + v.w * v.w;
  for (int off = 32; off; off >>= 1) ss += __shfl_down(ss, off, 64);
  __shared__ float w[4];
  const int lane = threadIdx.x & 63, wid = threadIdx.x >> 6;
  if (lane == 0) w[wid] = ss;
  __syncthreads();
  if (threadIdx.x == 0) {
    const float t = w[0] + w[1] + w[2] + w[3];
    scale[row] = 64.0f / fmaxf(sqrtf(t), NORM_EPSF);
  }
}

// ------------------------------------------------- fused GEMM + tile argmax
// grid = 16384 blocks: blockIdx.x & 63 -> k-tile, >> 6 -> b-tile.
// Each block: 128x128 sims accumulated over D=1024 via split-fp16 MFMA,
// then per-row argmax over its 128 cols -> partial (val, idx) per k-tile.
__global__ __launch_bounds__(256) void gemm_argmax_kernel(
    const float* __restrict__ z, const float* __restrict__ cb,
    const float* __restrict__ scaleA, const float* __restrict__ scaleB,
    float* __restrict__ pval, int* __restrict__ pidx) {
  __shared__ _Float16 sAh[BT * LDT];
  __shared__ _Float16 sAl[BT * LDT];
  __shared__ _Float16 sBh[KT * LDT];
  __shared__ _Float16 sBl[KT * LDT];
  __shared__ float sSA[BT];
  __shared__ float sSB[KT];
  __shared__ float smv[BT][2];
  __shared__ int smc[BT][2];

  const int tid = threadIdx.x;
  const int kt = blockIdx.x & (NKT - 1);
  const int bt = blockIdx.x >> 6;
  const int b0 = bt * BT;
  const int k0 = kt * KT;

  if (tid < 128) sSA[tid] = scaleA[b0 + tid];
  else           sSB[tid - 128] = scaleB[k0 + tid - 128];
  __syncthreads();

  const int lane = tid & 63;
  const int q = lane >> 4;      // quad 0..3
  const int ln = lane & 15;     // lane-in-16
  const int wid = tid >> 6;     // wave 0..3
  const int wm = wid >> 1;      // wave row (b) half
  const int wn = wid & 1;       // wave col (k) half

  f32x4 acc[4][4];
#pragma unroll
  for (int i = 0; i < 4; ++i)
#pragma unroll
    for (int j = 0; j < 4; ++j) acc[i][j] = (f32x4){0.f, 0.f, 0.f, 0.f};

  for (int it = 0; it < D_N / DT; ++it) {
    const int d0 = it * DT;
    // --- stage: load fp32, scale, split into hi/lo fp16 planes in LDS.
    // 128 rows x 32 floats = 1024 float4 chunks per operand; 4 per thread.
#pragma unroll
    for (int c = 0; c < 4; ++c) {
      const int ch = tid + c * 256;
      const int row = ch >> 3;
      const int seg = (ch & 7) << 2;
      {
        float4 v = *reinterpret_cast<const float4*>(
            z + (size_t)(b0 + row) * D_N + d0 + seg);
        const float s = sSA[row];
        const float x0 = v.x * s, x1 = v.y * s, x2 = v.z * s, x3 = v.w * s;
        f16x4 h, l;
        h[0] = (_Float16)x0; l[0] = (_Float16)(x0 - (float)h[0]);
        h[1] = (_Float16)x1; l[1] = (_Float16)(x1 - (float)h[1]);
        h[2] = (_Float16)x2; l[2] = (_Float16)(x2 - (float)h[2]);
        h[3] = (_Float16)x3; l[3] = (_Float16)(x3 - (float)h[3]);
        *reinterpret_cast<f16x4*>(&sAh[row * LDT + seg]) = h;
        *reinterpret_cast<f16x4*>(&sAl[row * LDT + seg]) = l;
      }
      {
        float4 v = *reinterpret_cast<const float4*>(
            cb + (size_t)(k0 + row) * D_N + d0 + seg);
        const float s = sSB[row];
        const float x0 = v.x * s, x1 = v.y * s, x2 = v.z * s, x3 = v.w * s;
        f16x4 h, l;
        h[0] = (_Float16)x0; l[0] = (_Float16)(x0 - (float)h[0]);
        h[1] = (_Float16)x1; l[1] = (_Float16)(x1 - (float)h[1]);
        h[2] = (_Float16)x2; l[2] = (_Float16)(x2 - (float)h[2]);
        h[3] = (_Float16)x3; l[3] = (_Float16)(x3 - (float)h[3]);
        *reinterpret_cast<f16x4*>(&sBh[row * LDT + seg]) = h;
        *reinterpret_cast<f16x4*>(&sBl[row * LDT + seg]) = l;
      }
    }
    __syncthreads();

    // --- fragments: A[m=ln][k=q*8+j], B[k=q*8+j][n=ln]; both tiles stored
    // [row][d] so the addressing is identical.
    f16x8 ah[4], al[4], bh[4], bl[4];
#pragma unroll
    for (int i = 0; i < 4; ++i) {
      const int r = wm * 64 + i * 16 + ln;
      ah[i] = *reinterpret_cast<const f16x8*>(&sAh[r * LDT + q * 8]);
      al[i] = *reinterpret_cast<const f16x8*>(&sAl[r * LDT + q * 8]);
    }
#pragma unroll
    for (int j = 0; j < 4; ++j) {
      const int r = wn * 64 + j * 16 + ln;
      bh[j] = *reinterpret_cast<const f16x8*>(&sBh[r * LDT + q * 8]);
      bl[j] = *reinterpret_cast<const f16x8*>(&sBl[r * LDT + q * 8]);
    }
#pragma unroll
    for (int i = 0; i < 4; ++i)
#pragma unroll
      for (int j = 0; j < 4; ++j) {
        acc[i][j] = __builtin_amdgcn_mfma_f32_16x16x32_f16(ah[i], bh[j],
                                                           acc[i][j], 0, 0, 0);
        acc[i][j] = __builtin_amdgcn_mfma_f32_16x16x32_f16(ah[i], bl[j],
                                                           acc[i][j], 0, 0, 0);
        acc[i][j] = __builtin_amdgcn_mfma_f32_16x16x32_f16(al[i], bh[j],
                                                           acc[i][j], 0, 0, 0);
      }
    __syncthreads();
  }

  // --- per-row argmax over this block's 128 cols.
  // C/D layout: col = ln, row = q*4 + reg.  np.argmax tie-break: lowest index.
#pragma unroll
  for (int i = 0; i < 4; ++i) {
#pragma unroll
    for (int r = 0; r < 4; ++r) {
      float bv = -3.402823466e38f;
      int bc = 0;
#pragma unroll
      for (int j = 0; j < 4; ++j) {   // ascending col within lane
        const float v = acc[i][j][r];
        const int c = wn * 64 + j * 16 + ln;
        if (v > bv) { bv = v; bc = c; }
      }
      for (int m = 1; m < 16; m <<= 1) {   // butterfly across the 16 cols
        const float ov = __shfl_xor(bv, m, 16);
        const int oc = __shfl_xor(bc, m, 16);
        if (ov > bv || (ov == bv && oc < bc)) { bv = ov; bc = oc; }
      }
      if (ln == 0) {
        const int row = wm * 64 + i * 16 + q * 4 + r;
        smv[row][wn] = bv;
        smc[row][wn] = bc;
      }
    }
  }
  __syncthreads();
  if (tid < 128) {
    const float v0 = smv[tid][0], v1 = smv[tid][1];
    const int c0 = smc[tid][0], c1 = smc[tid][1];
    float bv; int bc;
    if (v1 > v0) { bv = v1; bc = c1; } else { bv = v0; bc = c0; }  // tie -> lower col
    const size_t o = (size_t)kt * B_N + b0 + tid;
    pval[o] = bv;
    pidx[o] = k0 + bc;
  }
}

// ------------------------------------------ cross-tile argmax + histogram
__global__ __launch_bounds__(256) void reduce_argmax_kernel(
    const float* __restrict__ pval, const int* __restrict__ pidx,
    int* __restrict__ ids, float* __restrict__ out_ids,
    float* __restrict__ counts) {
  const int b = blockIdx.x * 256 + threadIdx.x;
  float bv = -3.402823466e38f;
  int bc = 0;
  for (int kt = 0; kt < NKT; ++kt) {   // ascending k-tile: tie -> earliest
    const float v = pval[(size_t)kt * B_N + b];
    if (v > bv) { bv = v; bc = pidx[(size_t)kt * B_N + b]; }
  }
  ids[b] = bc;
  out_ids[b] = (float)bc;
  atomicAdd(&counts[bc], 1.0f);
}

// ------------------- gather q, z_q out, loss partials, scatter-add sum_k
__global__ __launch_bounds__(256) void quant_scatter_kernel(
    const float* __restrict__ z, const float* __restrict__ cb,
    const int* __restrict__ ids, float* __restrict__ zq_out,
    float* __restrict__ sumk, double* __restrict__ loss_part) {
  double lsum = 0.0;
  const size_t total = (size_t)B_N * D_N;
  for (size_t idx = (size_t)blockIdx.x * 256 + threadIdx.x; idx < total;
       idx += (size_t)gridDim.x * 256) {
    const int b = (int)(idx >> 10);
    const int d = (int)(idx & 1023);
    const int id = ids[b];
    const float zv = z[idx];
    const float qv = cb[(size_t)id * D_N + d];
    const float t = qv - zv;          // replicate z + (q - z) rounding
    zq_out[idx] = zv + t;
    const float df = zv - qv;
    const float sq = df * df;         // squared in fp32 like np
    lsum += (double)sq;
    atomicAdd(&sumk[(size_t)id * D_N + d], zv);
  }
  for (int off = 32; off; off >>= 1) lsum += __shfl_down(lsum, off, 64);
  __shared__ double w[4];
  const int lane = threadIdx.x & 63, wid = threadIdx.x >> 6;
  if (lane == 0) w[wid] = lsum;
  __syncthreads();
  if (threadIdx.x == 0) loss_part[blockIdx.x] = w[0] + w[1] + w[2] + w[3];
}

// ----------------------------------------------------------- EMA finalize
__global__ __launch_bounds__(256) void finalize_kernel(
    const float* __restrict__ ema_count, const float* __restrict__ ema_weight,
    const float* __restrict__ counts, const float* __restrict__ sumk,
    float* __restrict__ out_codebook, float* __restrict__ out_count,
    float* __restrict__ out_weight) {
  const size_t idx = (size_t)blockIdx.x * 256 + threadIdx.x;
  const int k = (int)(idx >> 10);
  const float w = DECAYF * ema_weight[idx] + OMDECAYF * sumk[idx];
  const float nc = DECAYF * ema_count[k] + OMDECAYF * counts[k];
  out_weight[idx] = w;
  out_codebook[idx] = w / (nc + EPSF);
  if ((idx & 1023) == 0) out_count[k] = nc;
}

// ------------------------------------------------------------ loss finalize
__global__ __launch_bounds__(256) void loss_kernel(
    const double* __restrict__ loss_part, float* __restrict__ out_loss, int n) {
  double s = 0.0;
  for (int i = threadIdx.x; i < n; i += 256) s += loss_part[i];
  for (int off = 32; off; off >>= 1) s += __shfl_down(s, off, 64);
  __shared__ double w[4];
  const int lane = threadIdx.x & 63, wid = threadIdx.x >> 6;
  if (lane == 0) w[wid] = s;
  __syncthreads();
  if (threadIdx.x == 0) {
    const double tot = w[0] + w[1] + w[2] + w[3];
    out_loss[0] = (float)(0.25 * (tot / (double)((size_t)B_N * D_N)));
  }
}

extern "C" void kernel_launch(void* const* d_in, const int* in_sizes, int n_in,
                              void* d_out, int out_size, void* d_ws,
                              size_t ws_size, hipStream_t stream) {
  const float* z = (const float*)d_in[0];
  const float* cb = (const float*)d_in[1];
  const float* ema_count = (const float*)d_in[2];
  const float* ema_weight = (const float*)d_in[3];
  float* out = (float*)d_out;

  // output layout (return order, flat float32)
  const size_t o_zq = 0;                       // [B*D]
  const size_t o_ids = (size_t)B_N * D_N;      // [B]
  const size_t o_loss = o_ids + B_N;           // [1]
  const size_t o_cbk = o_loss + 1;             // [K*D]
  const size_t o_cnt = o_cbk + (size_t)K_N * D_N;  // [K]
  const size_t o_wt = o_cnt + K_N;             // [K*D]

  // workspace layout (~48.3 MB)
  char* ws = (char*)d_ws;
  float* scaleA = (float*)ws;                         // 131072 B
  float* scaleB = (float*)(ws + 131072);              // 32768 B
  float* pval = (float*)(ws + 163840);                // 8388608 B
  int* pidx = (int*)(ws + 8552448);                   // 8388608 B
  int* ids = (int*)(ws + 16941056);                   // 131072 B
  float* counts = (float*)(ws + 17072128);            // 32768 B
  float* sumk = (float*)(ws + 17104896);              // 33554432 B
  double* loss_part = (double*)(ws + 50659328);       // 32768 B

  row_scale_kernel<<<B_N, 256, 0, stream>>>(z, scaleA);
  row_scale_kernel<<<K_N, 256, 0, stream>>>(cb, scaleB);
  hipMemsetAsync(counts, 0, (size_t)K_N * sizeof(float), stream);
  hipMemsetAsync(sumk, 0, (size_t)K_N * D_N * sizeof(float), stream);

  gemm_argmax_kernel<<<(B_N / BT) * NKT, 256, 0, stream>>>(z, cb, scaleA,
                                                           scaleB, pval, pidx);
  reduce_argmax_kernel<<<B_N / 256, 256, 0, stream>>>(pval, pidx, ids,
                                                      out + o_ids, counts);
  quant_scatter_kernel<<<4096, 256, 0, stream>>>(z, cb, ids, out + o_zq, sumk,
                                                 loss_part);
  finalize_kernel<<<(K_N * D_N) / 256, 256, 0, stream>>>(
      ema_count, ema_weight, counts, sumk, out + o_cbk, out + o_cnt,
      out + o_wt);
  loss_kernel<<<1, 256, 0, stream>>>(loss_part, out + o_loss, 4096);
}

// Round 2
// 2044.637 us; speedup vs baseline: 1.1896x; 1.1896x over previous
//
#include <hip/hip_runtime.h>
#include <hip/hip_bf16.h>
#include <cstdint>
#include <cstddef>

// VQ-EMA fused pipeline for B=32768, K=8192, D=1024 on gfx950.
// sim = (z/||z||)@(cb/||cb||)^T + per-row argmax via split-fp16 MFMA
// (hi*hi + hi*lo + lo*hi), x64 pre-scale folded into the row norm.
// Round 2: cb pre-split to tile-ordered fp16 planes + global_load_lds
// staging for B; chunked conflict-free LDS layout; 4 blocks/CU.

#define B_N 32768
#define K_N 8192
#define D_N 1024
#define DECAYF 0.99f
#define OMDECAYF 0.01f
#define EPSF 1e-5f
#define NORM_EPSF 1e-12f

#define BT 128
#define KT 128
#define DT 32            // d per K-step
#define NKT (K_N / KT)   // 64 k-tiles
#define NIT (D_N / DT)   // 32 K-steps
// LDS tile: 512 chunks of 16B; chunk (q,r) at half-offset (q*128+r)*8
#define TILE_HALVES 4096

typedef _Float16 f16x8 __attribute__((ext_vector_type(8)));
typedef float f32x4 __attribute__((ext_vector_type(4)));

#define GLOAD_LDS16(gptr, lptr)                                         \
  __builtin_amdgcn_global_load_lds(                                     \
      (const __attribute__((address_space(1))) unsigned int*)(gptr),    \
      (__attribute__((address_space(3))) unsigned int*)(lptr), 16, 0, 0)

__device__ inline void split8(const float4 v0, const float4 v1, const float s,
                              f16x8& h, f16x8& l) {
  const float x[8] = {v0.x, v0.y, v0.z, v0.w, v1.x, v1.y, v1.z, v1.w};
#pragma unroll
  for (int k = 0; k < 8; ++k) {
    const float xs = x[k] * s;
    const _Float16 hh = (_Float16)xs;
    h[k] = hh;
    l[k] = (_Float16)(xs - (float)hh);
  }
}

// ---------------------------------------------------------------- row scales
__global__ __launch_bounds__(256) void row_scale_kernel(
    const float* __restrict__ x, float* __restrict__ scale) {
  const int row = blockIdx.x;
  const float4 v =
      reinterpret_cast<const float4*>(x + (size_t)row * D_N)[threadIdx.x];
  float ss = v.x * v.x + v.y * v.y + v.z * v.z + v.w * v.w;
  for (int off = 32; off; off >>= 1) ss += __shfl_down(ss, off, 64);
  __shared__ float w[4];
  const int lane = threadIdx.x & 63, wid = threadIdx.x >> 6;
  if (lane == 0) w[wid] = ss;
  __syncthreads();
  if (threadIdx.x == 0) {
    const float t = w[0] + w[1] + w[2] + w[3];
    scale[row] = 64.0f / fmaxf(sqrtf(t), NORM_EPSF);
  }
}

// ------------------------------------- pre-split cb into tile-ordered planes
// blockIdx.x = kt*32 + it. Tile = 512 chunks of 16B (8 halves); chunk p ->
// (q = p>>7, r = p&127); contents = fp16(cb[k0+r] * s) halves [it*32+q*8 ..+8].
// Stored contiguously: plane[(blockIdx.x*512 + p)*8]. GEMM staging then reads
// 1KB-contiguous wave chunks straight into LDS (layout matches by construction).
__global__ __launch_bounds__(256) void split_cb_kernel(
    const float* __restrict__ cb, const float* __restrict__ scale,
    _Float16* __restrict__ cbh_t, _Float16* __restrict__ cbl_t) {
  const int kt = blockIdx.x >> 5;
  const int it = blockIdx.x & 31;
  const int k0 = kt * KT;
  const int d0 = it * DT;
#pragma unroll
  for (int c = 0; c < 2; ++c) {
    const int p = threadIdx.x + c * 256;
    const int q = p >> 7, r = p & 127;
    const float s = scale[k0 + r];
    const float* src = cb + (size_t)(k0 + r) * D_N + d0 + q * 8;
    const float4 v0 = *reinterpret_cast<const float4*>(src);
    const float4 v1 = *reinterpret_cast<const float4*>(src + 4);
    f16x8 h, l;
    split8(v0, v1, s, h, l);
    const size_t o = ((size_t)blockIdx.x * 512 + p) * 8;
    *reinterpret_cast<f16x8*>(cbh_t + o) = h;
    *reinterpret_cast<f16x8*>(cbl_t + o) = l;
  }
}

// ------------------------------------------------- fused GEMM + tile argmax
__global__ __launch_bounds__(256, 4) void gemm_argmax_kernel(
    const float* __restrict__ z, const _Float16* __restrict__ cbh_t,
    const _Float16* __restrict__ cbl_t, const float* __restrict__ scaleA,
    float* __restrict__ pval, int* __restrict__ pidx) {
  __shared__ __align__(16) _Float16 sAh[TILE_HALVES];
  __shared__ __align__(16) _Float16 sAl[TILE_HALVES];
  __shared__ __align__(16) _Float16 sBh[TILE_HALVES];
  __shared__ __align__(16) _Float16 sBl[TILE_HALVES];
  __shared__ float sSA[BT];
  __shared__ float smv[BT][2];
  __shared__ int smc[BT][2];

  const int tid = threadIdx.x;
  const int kt = blockIdx.x & (NKT - 1);
  const int bt = blockIdx.x >> 6;
  const int b0 = bt * BT;
  const int k0 = kt * KT;

  if (tid < 128) sSA[tid] = scaleA[b0 + tid];

  const int lane = tid & 63;
  const int q = lane >> 4;
  const int ln = lane & 15;
  const int wid = tid >> 6;
  const int wm = wid >> 1;
  const int wn = wid & 1;

  // fragment LDS half-offsets (constant across K-steps)
  int aoff[4], boff[4];
#pragma unroll
  for (int i = 0; i < 4; ++i)
    aoff[i] = ((q << 7) + wm * 64 + i * 16 + ln) * 8;
#pragma unroll
  for (int j = 0; j < 4; ++j)
    boff[j] = ((q << 7) + wn * 64 + j * 16 + ln) * 8;

  // A staging: thread t handles chunks (sq, sr0) and (sq, sr0+64)
  const int sq = tid & 3;
  const int sr0 = tid >> 2;
  const float* zp0 = z + (size_t)(b0 + sr0) * D_N + sq * 8;
  const float* zp1 = z + (size_t)(b0 + sr0 + 64) * D_N + sq * 8;
  const int aw0 = ((sq << 7) + sr0) * 8;
  const int aw1 = ((sq << 7) + sr0 + 64) * 8;

  // B staging: per-lane global source; wave w covers chunks w*128 + {0,64} + lane
  const size_t bsrc = ((size_t)kt * NIT * 512 + wid * 128 + lane) * 8;
  const _Float16* bh_base = cbh_t + bsrc;
  const _Float16* bl_base = cbl_t + bsrc;
  _Float16* ldsBh0 = &sBh[wid * 1024];
  _Float16* ldsBh1 = &sBh[wid * 1024 + 512];
  _Float16* ldsBl0 = &sBl[wid * 1024];
  _Float16* ldsBl1 = &sBl[wid * 1024 + 512];

  f32x4 acc[4][4];
#pragma unroll
  for (int i = 0; i < 4; ++i)
#pragma unroll
    for (int j = 0; j < 4; ++j) acc[i][j] = (f32x4){0.f, 0.f, 0.f, 0.f};

  __syncthreads();  // sSA visible

  for (int it = 0; it < NIT; ++it) {
    // --- B: async global->LDS (4 x 1KB per wave), tile-ordered source
    const size_t tb = (size_t)it * TILE_HALVES;
    GLOAD_LDS16(bh_base + tb, ldsBh0);
    GLOAD_LDS16(bh_base + tb + 512, ldsBh1);
    GLOAD_LDS16(bl_base + tb, ldsBl0);
    GLOAD_LDS16(bl_base + tb + 512, ldsBl1);

    // --- A: fp32 load, scale+split, chunked LDS write (conflict-free)
    {
      const float s0 = sSA[sr0];
      const float4 v0 = *reinterpret_cast<const float4*>(zp0 + it * DT);
      const float4 v1 = *reinterpret_cast<const float4*>(zp0 + it * DT + 4);
      f16x8 h, l;
      split8(v0, v1, s0, h, l);
      *reinterpret_cast<f16x8*>(&sAh[aw0]) = h;
      *reinterpret_cast<f16x8*>(&sAl[aw0]) = l;
    }
    {
      const float s1 = sSA[sr0 + 64];
      const float4 v0 = *reinterpret_cast<const float4*>(zp1 + it * DT);
      const float4 v1 = *reinterpret_cast<const float4*>(zp1 + it * DT + 4);
      f16x8 h, l;
      split8(v0, v1, s1, h, l);
      *reinterpret_cast<f16x8*>(&sAh[aw1]) = h;
      *reinterpret_cast<f16x8*>(&sAl[aw1]) = l;
    }
    __syncthreads();  // drains vmcnt (global_load_lds) + lgkm (ds_write)

    f16x8 ah[4], al[4], bh[4], bl[4];
#pragma unroll
    for (int i = 0; i < 4; ++i) {
      ah[i] = *reinterpret_cast<const f16x8*>(&sAh[aoff[i]]);
      al[i] = *reinterpret_cast<const f16x8*>(&sAl[aoff[i]]);
    }
#pragma unroll
    for (int j = 0; j < 4; ++j) {
      bh[j] = *reinterpret_cast<const f16x8*>(&sBh[boff[j]]);
      bl[j] = *reinterpret_cast<const f16x8*>(&sBl[boff[j]]);
    }
#pragma unroll
    for (int i = 0; i < 4; ++i)
#pragma unroll
      for (int j = 0; j < 4; ++j) {
        acc[i][j] = __builtin_amdgcn_mfma_f32_16x16x32_f16(ah[i], bh[j],
                                                           acc[i][j], 0, 0, 0);
        acc[i][j] = __builtin_amdgcn_mfma_f32_16x16x32_f16(ah[i], bl[j],
                                                           acc[i][j], 0, 0, 0);
        acc[i][j] = __builtin_amdgcn_mfma_f32_16x16x32_f16(al[i], bh[j],
                                                           acc[i][j], 0, 0, 0);
      }
    __syncthreads();
  }

  // --- per-row argmax over this block's 128 cols.
  // C/D layout: col = ln, row = q*4 + reg. np.argmax tie-break: lowest index.
#pragma unroll
  for (int i = 0; i < 4; ++i) {
#pragma unroll
    for (int r = 0; r < 4; ++r) {
      float bv = -3.402823466e38f;
      int bc = 0;
#pragma unroll
      for (int j = 0; j < 4; ++j) {
        const float v = acc[i][j][r];
        const int c = wn * 64 + j * 16 + ln;
        if (v > bv) { bv = v; bc = c; }
      }
      for (int m = 1; m < 16; m <<= 1) {
        const float ov = __shfl_xor(bv, m, 16);
        const int oc = __shfl_xor(bc, m, 16);
        if (ov > bv || (ov == bv && oc < bc)) { bv = ov; bc = oc; }
      }
      if (ln == 0) {
        const int row = wm * 64 + i * 16 + q * 4 + r;
        smv[row][wn] = bv;
        smc[row][wn] = bc;
      }
    }
  }
  __syncthreads();
  if (tid < 128) {
    const float v0 = smv[tid][0], v1 = smv[tid][1];
    const int c0 = smc[tid][0], c1 = smc[tid][1];
    float bv; int bc;
    if (v1 > v0) { bv = v1; bc = c1; } else { bv = v0; bc = c0; }
    const size_t o = (size_t)kt * B_N + b0 + tid;
    pval[o] = bv;
    pidx[o] = k0 + bc;
  }
}

// ------------------------------------------ cross-tile argmax + histogram
__global__ __launch_bounds__(256) void reduce_argmax_kernel(
    const float* __restrict__ pval, const int* __restrict__ pidx,
    int* __restrict__ ids, float* __restrict__ out_ids,
    float* __restrict__ counts) {
  const int b = blockIdx.x * 256 + threadIdx.x;
  float bv = -3.402823466e38f;
  int bc = 0;
  for (int kt = 0; kt < NKT; ++kt) {
    const float v = pval[(size_t)kt * B_N + b];
    if (v > bv) { bv = v; bc = pidx[(size_t)kt * B_N + b]; }
  }
  ids[b] = bc;
  out_ids[b] = (float)bc;
  atomicAdd(&counts[bc], 1.0f);
}

// ------------------- gather q, z_q out, loss partials, scatter-add sum_k
__global__ __launch_bounds__(256) void quant_scatter_kernel(
    const float* __restrict__ z, const float* __restrict__ cb,
    const int* __restrict__ ids, float* __restrict__ zq_out,
    float* __restrict__ sumk, double* __restrict__ loss_part) {
  double lsum = 0.0;
  const size_t total = (size_t)B_N * D_N;
  for (size_t idx = (size_t)blockIdx.x * 256 + threadIdx.x; idx < total;
       idx += (size_t)gridDim.x * 256) {
    const int b = (int)(idx >> 10);
    const int d = (int)(idx & 1023);
    const int id = ids[b];
    const float zv = z[idx];
    const float qv = cb[(size_t)id * D_N + d];
    const float t = qv - zv;
    zq_out[idx] = zv + t;
    const float df = zv - qv;
    const float sq = df * df;
    lsum += (double)sq;
    atomicAdd(&sumk[(size_t)id * D_N + d], zv);
  }
  for (int off = 32; off; off >>= 1) lsum += __shfl_down(lsum, off, 64);
  __shared__ double w[4];
  const int lane = threadIdx.x & 63, wid = threadIdx.x >> 6;
  if (lane == 0) w[wid] = lsum;
  __syncthreads();
  if (threadIdx.x == 0) loss_part[blockIdx.x] = w[0] + w[1] + w[2] + w[3];
}

// ----------------------------------------------------------- EMA finalize
__global__ __launch_bounds__(256) void finalize_kernel(
    const float* __restrict__ ema_count, const float* __restrict__ ema_weight,
    const float* __restrict__ counts, const float* __restrict__ sumk,
    float* __restrict__ out_codebook, float* __restrict__ out_count,
    float* __restrict__ out_weight) {
  const size_t idx = (size_t)blockIdx.x * 256 + threadIdx.x;
  const int k = (int)(idx >> 10);
  const float w = DECAYF * ema_weight[idx] + OMDECAYF * sumk[idx];
  const float nc = DECAYF * ema_count[k] + OMDECAYF * counts[k];
  out_weight[idx] = w;
  out_codebook[idx] = w / (nc + EPSF);
  if ((idx & 1023) == 0) out_count[k] = nc;
}

// ------------------------------------------------------------ loss finalize
__global__ __launch_bounds__(256) void loss_kernel(
    const double* __restrict__ loss_part, float* __restrict__ out_loss, int n) {
  double s = 0.0;
  for (int i = threadIdx.x; i < n; i += 256) s += loss_part[i];
  for (int off = 32; off; off >>= 1) s += __shfl_down(s, off, 64);
  __shared__ double w[4];
  const int lane = threadIdx.x & 63, wid = threadIdx.x >> 6;
  if (lane == 0) w[wid] = s;
  __syncthreads();
  if (threadIdx.x == 0) {
    const double tot = w[0] + w[1] + w[2] + w[3];
    out_loss[0] = (float)(0.25 * (tot / (double)((size_t)B_N * D_N)));
  }
}

extern "C" void kernel_launch(void* const* d_in, const int* in_sizes, int n_in,
                              void* d_out, int out_size, void* d_ws,
                              size_t ws_size, hipStream_t stream) {
  const float* z = (const float*)d_in[0];
  const float* cb = (const float*)d_in[1];
  const float* ema_count = (const float*)d_in[2];
  const float* ema_weight = (const float*)d_in[3];
  float* out = (float*)d_out;

  // output layout (return order, flat float32)
  const size_t o_zq = 0;
  const size_t o_ids = (size_t)B_N * D_N;
  const size_t o_loss = o_ids + B_N;
  const size_t o_cbk = o_loss + 1;
  const size_t o_cnt = o_cbk + (size_t)K_N * D_N;
  const size_t o_wt = o_cnt + K_N;

  // workspace layout (~84.2 MB)
  char* ws = (char*)d_ws;
  float* scaleA = (float*)ws;                        // 131072 B
  float* scaleB = (float*)(ws + 131072);             // 32768 B
  float* pval = (float*)(ws + 163840);               // 8388608 B
  int* pidx = (int*)(ws + 8552448);                  // 8388608 B
  int* ids = (int*)(ws + 16941056);                  // 131072 B
  float* counts = (float*)(ws + 17072128);           // 32768 B
  float* sumk = (float*)(ws + 17104896);             // 33554432 B
  double* loss_part = (double*)(ws + 50659328);      // 32768 B
  _Float16* cbh_t = (_Float16*)(ws + 50692096);      // 16777216 B
  _Float16* cbl_t = (_Float16*)(ws + 67469312);      // 16777216 B

  row_scale_kernel<<<B_N, 256, 0, stream>>>(z, scaleA);
  row_scale_kernel<<<K_N, 256, 0, stream>>>(cb, scaleB);
  split_cb_kernel<<<NKT * NIT, 256, 0, stream>>>(cb, scaleB, cbh_t, cbl_t);
  hipMemsetAsync(counts, 0, (size_t)K_N * sizeof(float), stream);
  hipMemsetAsync(sumk, 0, (size_t)K_N * D_N * sizeof(float), stream);

  gemm_argmax_kernel<<<(B_N / BT) * NKT, 256, 0, stream>>>(z, cbh_t, cbl_t,
                                                           scaleA, pval, pidx);
  reduce_argmax_kernel<<<B_N / 256, 256, 0, stream>>>(pval, pidx, ids,
                                                      out + o_ids, counts);
  quant_scatter_kernel<<<4096, 256, 0, stream>>>(z, cb, ids, out + o_zq, sumk,
                                                 loss_part);
  finalize_kernel<<<(K_N * D_N) / 256, 256, 0, stream>>>(
      ema_count, ema_weight, counts, sumk, out + o_cbk, out + o_cnt,
      out + o_wt);
  loss_kernel<<<1, 256, 0, stream>>>(loss_part, out + o_loss, 4096);
}